// Round 1
// baseline (298.323 us; speedup 1.0000x reference)
//
#include <hip/hip_runtime.h>
#include <math.h>

#define N_BOXES 256
#define N_VIEWS 6
#define C_FEAT 256
#define HF 116
#define WF 200
#define P_TOT (N_BOXES * N_VIEWS)
#define EPS_F 1e-8f

// Workspace layout (poisoned to 0xAA before each timed call -> kernel 1 must init everything)
struct WsLayout {
    int   first;
    float norm_stored;     // fmaxf(||stored||, EPS)
    float total;
    int   count;
    int   done;
    int   pad[3];
    float stored[C_FEAT];  // fm[first]
    int   packed[P_TOT];   // bit31 = valid, bits[15:9] = v0c, bits[8:0] = u0c
};

__device__ __forceinline__ float wave_reduce_sum(float v) {
    #pragma unroll
    for (int off = 32; off > 0; off >>= 1)
        v += __shfl_down(v, off, 64);
    return v;
}

// Kernel 1: single block. Projections for all P points, argmax(valid) -> first,
// gather stored = fm[first], its norm; init accumulators.
__global__ __launch_bounds__(256) void proj_kernel(
    const float* __restrict__ boxes,   // (N,7)
    const float* __restrict__ feats,   // (V,C,HF,WF)
    const float* __restrict__ Km,      // (V,3,3)
    const float* __restrict__ Tm,      // (V,4,4)
    const int*   __restrict__ img,     // (V,2) [H, W]
    WsLayout*    __restrict__ ws)
{
    __shared__ int   s_packed[P_TOT];
    __shared__ int   s_first;
    __shared__ float s_red[4];
    const int tid = threadIdx.x;
    if (tid == 0) s_first = 0x7fffffff;
    __syncthreads();

    int localmin = 0x7fffffff;
    for (int p = tid; p < P_TOT; p += 256) {
        const int n = p / N_VIEWS, v = p % N_VIEWS;
        const float cx = boxes[n * 7 + 0];
        const float cy = boxes[n * 7 + 1];
        const float cz = boxes[n * 7 + 2];
        const float* Tv = Tm + v * 16;
        const float* Kv = Km + v * 9;
        float pc[3];
        #pragma unroll
        for (int i = 0; i < 3; ++i)
            pc[i] = Tv[i * 4 + 0] * cx + Tv[i * 4 + 1] * cy + Tv[i * 4 + 2] * cz + Tv[i * 4 + 3];
        float p2[3];
        #pragma unroll
        for (int i = 0; i < 3; ++i)
            p2[i] = Kv[i * 3 + 0] * pc[0] + Kv[i * 3 + 1] * pc[1] + Kv[i * 3 + 2] * pc[2];
        const float z  = pc[2];
        const float uu = p2[0] / p2[2];
        const float vv = p2[1] / z;
        const float Wimg = (float)img[v * 2 + 1];
        const float Himg = (float)img[v * 2 + 0];
        const float us = uu * (float)WF / Wimg;
        const float vs = vv * (float)HF / Himg;
        const int u0 = (int)floorf(us);
        const int v0 = (int)floorf(vs);
        const bool valid = (z > 0.f) && (uu >= 0.f) && (uu < Wimg) &&
                           (vv >= 0.f) && (vv < Himg) &&
                           (u0 < WF - 1) && (v0 < HF - 1);
        const int u0c = min(max(u0, 0), WF - 2);
        const int v0c = min(max(v0, 0), HF - 2);
        const int pk = u0c | (v0c << 9) | (valid ? (int)0x80000000 : 0);
        s_packed[p]   = pk;
        ws->packed[p] = pk;
        if (valid && p < localmin) localmin = p;
    }
    atomicMin(&s_first, localmin);
    __syncthreads();

    const int first = (s_first == 0x7fffffff) ? 0 : s_first;
    if (tid == 0) {
        ws->first = first;
        ws->total = 0.f;
        ws->count = 0;
        ws->done  = 0;
    }

    // gather stored = fm[first]; thread = channel
    const int pk = s_packed[first];
    const int x = pk & 0x1ff, y = (pk >> 9) & 0x7f;
    const int v = first % N_VIEWS;
    const float* base = feats + ((size_t)(v * C_FEAT + tid) * HF + y) * WF + x;
    const float fm = 0.25f * (base[0] + base[1] + base[WF] + base[WF + 1]);
    ws->stored[tid] = fm;

    float s = wave_reduce_sum(fm * fm);
    const int lane = tid & 63, wave = tid >> 6;
    if (lane == 0) s_red[wave] = s;
    __syncthreads();
    if (tid == 0) {
        const float nsq = s_red[0] + s_red[1] + s_red[2] + s_red[3];
        ws->norm_stored = fmaxf(sqrtf(nsq), EPS_F);
    }
}

// Kernel 2: one block per point. Gather fm on the fly, dot with stored, norm,
// accumulate masked loss; last block finishes the division and writes out.
__global__ __launch_bounds__(256) void loss_kernel(
    const float* __restrict__ feats,
    WsLayout*    __restrict__ ws,
    float*       __restrict__ out)
{
    const int p   = blockIdx.x;
    const int tid = threadIdx.x;
    const int first = ws->first;
    const int pk    = ws->packed[p];
    const bool active = (pk < 0) && (p != first);   // valid && not-first

    float dotp = 0.f, sqp = 0.f;
    if (active) {
        const int x = pk & 0x1ff, y = (pk >> 9) & 0x7f;
        const int v = p % N_VIEWS;
        const float* base = feats + ((size_t)(v * C_FEAT + tid) * HF + y) * WF + x;
        const float fm = 0.25f * (base[0] + base[1] + base[WF] + base[WF + 1]);
        const float s  = ws->stored[tid];
        dotp = fm * s;
        sqp  = fm * fm;
    }
    dotp = wave_reduce_sum(dotp);
    sqp  = wave_reduce_sum(sqp);

    __shared__ float s_red[2][4];
    const int lane = tid & 63, wave = tid >> 6;
    if (lane == 0) { s_red[0][wave] = dotp; s_red[1][wave] = sqp; }
    __syncthreads();

    if (tid == 0) {
        if (active) {
            const float dot = s_red[0][0] + s_red[0][1] + s_red[0][2] + s_red[0][3];
            const float nsq = s_red[1][0] + s_red[1][1] + s_red[1][2] + s_red[1][3];
            const float cosv = dot / (fmaxf(sqrtf(nsq), EPS_F) * ws->norm_stored);
            atomicAdd(&ws->total, 1.0f - cosv);
            atomicAdd(&ws->count, 1);
        }
        __threadfence();
        const int t = atomicAdd(&ws->done, 1);
        if (t == (int)gridDim.x - 1) {
            const float tot = atomicAdd(&ws->total, 0.0f);
            const int   cnt = atomicAdd(&ws->count, 0);
            out[0] = (cnt > 0) ? tot / (float)cnt : 0.0f;
        }
    }
}

extern "C" void kernel_launch(void* const* d_in, const int* in_sizes, int n_in,
                              void* d_out, int out_size, void* d_ws, size_t ws_size,
                              hipStream_t stream) {
    const float* boxes = (const float*)d_in[0];
    const float* feats = (const float*)d_in[1];
    const float* Km    = (const float*)d_in[2];
    const float* Tm    = (const float*)d_in[3];
    const int*   img   = (const int*)d_in[4];
    float* out = (float*)d_out;
    WsLayout* ws = (WsLayout*)d_ws;

    hipLaunchKernelGGL(proj_kernel, dim3(1), dim3(256), 0, stream,
                       boxes, feats, Km, Tm, img, ws);
    hipLaunchKernelGGL(loss_kernel, dim3(P_TOT), dim3(256), 0, stream,
                       feats, ws, out);
}

// Round 2
// 211.525 us; speedup vs baseline: 1.4103x; 1.4103x over previous
//
#include <hip/hip_runtime.h>
#include <math.h>

#define N_BOXES 256
#define N_VIEWS 6
#define C_FEAT 256
#define HF 116
#define WF 200
#define P_TOT (N_BOXES * N_VIEWS)
#define EPS_F 1e-8f

// Workspace (re-poisoned to 0xAA before every timed call; kernel 1/2 init all fields used)
struct WsLayout {
    int   first;
    float norm_stored;      // fmaxf(||stored||, EPS)
    int   count;            // n_pairs = n_valid - (any_valid ? 1 : 0)
    int   pad;
    float stored[C_FEAT];   // fm[first]
    int   packed[P_TOT];    // bit31 = valid, bits[15:9] = v0c, bits[8:0] = u0c
    float loss[P_TOT];      // per-point masked loss (0 if inactive)
};

__device__ __forceinline__ float wave_reduce_sum(float v) {
    #pragma unroll
    for (int off = 32; off > 0; off >>= 1)
        v += __shfl_down(v, off, 64);
    return v;
}

// Kernel 1: single block. Projections, first=argmax(valid), pair count,
// stored = fm[first], norm_stored.
__global__ __launch_bounds__(256) void proj_kernel(
    const float* __restrict__ boxes,   // (N,7)
    const float* __restrict__ feats,   // (V,C,HF,WF)
    const float* __restrict__ Km,      // (V,3,3)
    const float* __restrict__ Tm,      // (V,4,4)
    const int*   __restrict__ img,     // (V,2) [H,W]
    WsLayout*    __restrict__ ws)
{
    __shared__ int   s_packed[P_TOT];
    __shared__ int   s_first;
    __shared__ int   s_cnt;
    __shared__ float s_red[4];
    const int tid = threadIdx.x;
    if (tid == 0) { s_first = 0x7fffffff; s_cnt = 0; }
    __syncthreads();

    int localmin = 0x7fffffff;
    int localcnt = 0;
    for (int p = tid; p < P_TOT; p += 256) {
        const int n = p / N_VIEWS, v = p % N_VIEWS;
        const float cx = boxes[n * 7 + 0];
        const float cy = boxes[n * 7 + 1];
        const float cz = boxes[n * 7 + 2];
        const float* Tv = Tm + v * 16;
        const float* Kv = Km + v * 9;
        float pc[3];
        #pragma unroll
        for (int i = 0; i < 3; ++i)
            pc[i] = Tv[i * 4 + 0] * cx + Tv[i * 4 + 1] * cy + Tv[i * 4 + 2] * cz + Tv[i * 4 + 3];
        float p2[3];
        #pragma unroll
        for (int i = 0; i < 3; ++i)
            p2[i] = Kv[i * 3 + 0] * pc[0] + Kv[i * 3 + 1] * pc[1] + Kv[i * 3 + 2] * pc[2];
        const float z  = pc[2];
        const float uu = p2[0] / p2[2];
        const float vv = p2[1] / z;
        const float Wimg = (float)img[v * 2 + 1];
        const float Himg = (float)img[v * 2 + 0];
        const float us = uu * (float)WF / Wimg;
        const float vs = vv * (float)HF / Himg;
        const int u0 = (int)floorf(us);
        const int v0 = (int)floorf(vs);
        const bool valid = (z > 0.f) && (uu >= 0.f) && (uu < Wimg) &&
                           (vv >= 0.f) && (vv < Himg) &&
                           (u0 < WF - 1) && (v0 < HF - 1);
        const int u0c = min(max(u0, 0), WF - 2);
        const int v0c = min(max(v0, 0), HF - 2);
        const int pk = u0c | (v0c << 9) | (valid ? (int)0x80000000 : 0);
        s_packed[p]   = pk;
        ws->packed[p] = pk;
        if (valid) {
            ++localcnt;
            if (p < localmin) localmin = p;
        }
    }
    if (localmin != 0x7fffffff) atomicMin(&s_first, localmin);
    if (localcnt) atomicAdd(&s_cnt, localcnt);
    __syncthreads();

    const bool any_valid = (s_first != 0x7fffffff);
    const int first = any_valid ? s_first : 0;
    if (tid == 0) {
        ws->first = first;
        ws->count = s_cnt - (any_valid ? 1 : 0);
    }

    // stored = fm[first]; thread = channel
    const int pk = s_packed[first];
    const int x = pk & 0x1ff, y = (pk >> 9) & 0x7f;
    const int v = first % N_VIEWS;
    const float* base = feats + ((size_t)(v * C_FEAT + tid) * HF + y) * WF + x;
    const float fm = 0.25f * (base[0] + base[1] + base[WF] + base[WF + 1]);
    ws->stored[tid] = fm;

    float s = wave_reduce_sum(fm * fm);
    const int lane = tid & 63, wave = tid >> 6;
    if (lane == 0) s_red[wave] = s;
    __syncthreads();
    if (tid == 0) {
        const float nsq = s_red[0] + s_red[1] + s_red[2] + s_red[3];
        ws->norm_stored = fmaxf(sqrtf(nsq), EPS_F);
    }
}

// Kernel 2: one WAVE per point (4 points/block). Each lane covers 4 channels,
// 16 independent loads in flight; pure shfl reduction; uncontended store of
// the per-point loss. No block-level sync, no atomics.
__global__ __launch_bounds__(256) void gather_kernel(
    const float* __restrict__ feats,
    WsLayout*    __restrict__ ws)
{
    const int lane = threadIdx.x & 63;
    const int wave = threadIdx.x >> 6;
    const int p    = blockIdx.x * 4 + wave;

    const int first = ws->first;
    const int pk    = ws->packed[p];
    const bool active = (pk < 0) && (p != first);

    float dot = 0.f, nsq = 0.f;
    if (active) {
        const int x = pk & 0x1ff, y = (pk >> 9) & 0x7f;
        const int v = p % N_VIEWS;
        const float* base0 = feats + ((size_t)(v * C_FEAT) * HF + y) * WF + x;
        #pragma unroll
        for (int j = 0; j < 4; ++j) {
            const int c = lane + 64 * j;
            const float* b = base0 + (size_t)c * (HF * WF);
            const float fm = 0.25f * (b[0] + b[1] + b[WF] + b[WF + 1]);
            const float s  = ws->stored[c];
            dot += fm * s;
            nsq += fm * fm;
        }
    }
    dot = wave_reduce_sum(dot);
    nsq = wave_reduce_sum(nsq);

    if (lane == 0) {
        float l = 0.f;
        if (active)
            l = 1.0f - dot / (fmaxf(sqrtf(nsq), EPS_F) * ws->norm_stored);
        ws->loss[p] = l;
    }
}

// Kernel 3: single block reduces the 1536 per-point losses, divides, writes out.
__global__ __launch_bounds__(256) void finish_kernel(
    const WsLayout* __restrict__ ws,
    float*          __restrict__ out)
{
    __shared__ float s_red[4];
    const int tid = threadIdx.x;
    float s = 0.f;
    for (int p = tid; p < P_TOT; p += 256) s += ws->loss[p];
    s = wave_reduce_sum(s);
    const int lane = tid & 63, wave = tid >> 6;
    if (lane == 0) s_red[wave] = s;
    __syncthreads();
    if (tid == 0) {
        const float total = s_red[0] + s_red[1] + s_red[2] + s_red[3];
        const int   cnt   = ws->count;
        out[0] = (cnt > 0) ? total / (float)cnt : 0.0f;
    }
}

extern "C" void kernel_launch(void* const* d_in, const int* in_sizes, int n_in,
                              void* d_out, int out_size, void* d_ws, size_t ws_size,
                              hipStream_t stream) {
    const float* boxes = (const float*)d_in[0];
    const float* feats = (const float*)d_in[1];
    const float* Km    = (const float*)d_in[2];
    const float* Tm    = (const float*)d_in[3];
    const int*   img   = (const int*)d_in[4];
    float* out = (float*)d_out;
    WsLayout* ws = (WsLayout*)d_ws;

    hipLaunchKernelGGL(proj_kernel, dim3(1), dim3(256), 0, stream,
                       boxes, feats, Km, Tm, img, ws);
    hipLaunchKernelGGL(gather_kernel, dim3(P_TOT / 4), dim3(256), 0, stream,
                       feats, ws);
    hipLaunchKernelGGL(finish_kernel, dim3(1), dim3(256), 0, stream,
                       ws, out);
}

// Round 3
// 205.807 us; speedup vs baseline: 1.4495x; 1.0278x over previous
//
#include <hip/hip_runtime.h>
#include <math.h>

#define N_BOXES 256
#define N_VIEWS 6
#define C_FEAT 256
#define HF 116
#define WF 200
#define P_TOT (N_BOXES * N_VIEWS)
#define EPS_F 1e-8f

// Workspace (re-poisoned to 0xAA before every timed call; every field written each call)
struct WsLayout {
    int   count;           // n_pairs
    int   pad[15];
    float loss[P_TOT];     // per-point masked loss (0 if inactive)
};

__device__ __forceinline__ float wave_reduce_sum(float v) {
    #pragma unroll
    for (int off = 32; off > 0; off >>= 1)
        v += __shfl_down(v, off, 64);
    return v;
}

// Project point p (= box n, view v), return packed code:
// bit31 = valid, bits[15:9] = v0c (row), bits[8:0] = u0c (col).
// Pure ALU from ~8 KB of L1/L2-resident inputs — cheap to recompute per block.
__device__ __forceinline__ int project_pack(
    const float* __restrict__ boxes, const float* __restrict__ Km,
    const float* __restrict__ Tm, const int* __restrict__ img, int p)
{
    const int n = p / N_VIEWS, v = p - n * N_VIEWS;
    const float cx = boxes[n * 7 + 0];
    const float cy = boxes[n * 7 + 1];
    const float cz = boxes[n * 7 + 2];
    const float* Tv = Tm + v * 16;
    const float* Kv = Km + v * 9;
    float pc[3];
    #pragma unroll
    for (int i = 0; i < 3; ++i)
        pc[i] = Tv[i * 4 + 0] * cx + Tv[i * 4 + 1] * cy + Tv[i * 4 + 2] * cz + Tv[i * 4 + 3];
    float p2[3];
    #pragma unroll
    for (int i = 0; i < 3; ++i)
        p2[i] = Kv[i * 3 + 0] * pc[0] + Kv[i * 3 + 1] * pc[1] + Kv[i * 3 + 2] * pc[2];
    const float z  = pc[2];
    const float uu = p2[0] / p2[2];
    const float vv = p2[1] / z;
    const float Wimg = (float)img[v * 2 + 1];
    const float Himg = (float)img[v * 2 + 0];
    const int u0 = (int)floorf(uu * (float)WF / Wimg);
    const int v0 = (int)floorf(vv * (float)HF / Himg);
    const bool valid = (z > 0.f) && (uu >= 0.f) && (uu < Wimg) &&
                       (vv >= 0.f) && (vv < Himg) &&
                       (u0 < WF - 1) && (v0 < HF - 1);
    const int u0c = min(max(u0, 0), WF - 2);
    const int v0c = min(max(v0, 0), HF - 2);
    return u0c | (v0c << 9) | (valid ? (int)0x80000000 : 0);
}

// Main kernel: 384 blocks x 256 threads, one WAVE per point.
// Phase 1: every block redundantly computes first/count over all 1536 points.
// Phase 2: each wave gathers its point's fm AND the stored (first) fm,
//          reduces dot/nsq/snsq via shfl, stores an uncontended per-point loss.
__global__ __launch_bounds__(256) void fused_kernel(
    const float* __restrict__ boxes,   // (N,7)
    const float* __restrict__ feats,   // (V,C,HF,WF)
    const float* __restrict__ Km,      // (V,3,3)
    const float* __restrict__ Tm,      // (V,4,4)
    const int*   __restrict__ img,     // (V,2) [H,W]
    WsLayout*    __restrict__ ws)
{
    const int tid  = threadIdx.x;
    const int lane = tid & 63;
    const int wave = tid >> 6;

    // ---- Phase 1: first = argmax(valid), count = n_valid (block-redundant) ----
    int localmin = 0x7fffffff;
    int localcnt = 0;
    #pragma unroll
    for (int i = 0; i < P_TOT / 256; ++i) {
        const int p  = tid + 256 * i;
        const int pk = project_pack(boxes, Km, Tm, img, p);
        if (pk < 0) { ++localcnt; if (p < localmin) localmin = p; }
    }
    #pragma unroll
    for (int off = 32; off > 0; off >>= 1) {
        localmin = min(localmin, __shfl_down(localmin, off, 64));
        localcnt += __shfl_down(localcnt, off, 64);
    }
    __shared__ int s_min[4], s_cnt[4];
    if (lane == 0) { s_min[wave] = localmin; s_cnt[wave] = localcnt; }
    __syncthreads();
    const int gmin = min(min(s_min[0], s_min[1]), min(s_min[2], s_min[3]));
    const int gcnt = s_cnt[0] + s_cnt[1] + s_cnt[2] + s_cnt[3];
    const bool any_valid = (gmin != 0x7fffffff);
    const int first = any_valid ? gmin : 0;

    if (blockIdx.x == 0 && tid == 0)
        ws->count = gcnt - (any_valid ? 1 : 0);

    // ---- Phase 2: wave-per-point gather + cosine loss ----
    const int p = blockIdx.x * 4 + wave;
    const int pk_p = project_pack(boxes, Km, Tm, img, p);
    const int pk_f = project_pack(boxes, Km, Tm, img, first);
    const bool active = (pk_p < 0) && (p != first);

    float dot = 0.f, nsq = 0.f, snsq = 0.f;
    if (active) {
        const int xp = pk_p & 0x1ff, yp = (pk_p >> 9) & 0x7f;
        const int xf = pk_f & 0x1ff, yf = (pk_f >> 9) & 0x7f;
        const int vp = p % N_VIEWS;
        const int vf = first % N_VIEWS;
        const float* basep = feats + ((size_t)(vp * C_FEAT) * HF + yp) * WF + xp;
        const float* basef = feats + ((size_t)(vf * C_FEAT) * HF + yf) * WF + xf;
        #pragma unroll
        for (int j = 0; j < 4; ++j) {
            const int c = lane + 64 * j;
            const float* bp = basep + (size_t)c * (HF * WF);
            const float* bf = basef + (size_t)c * (HF * WF);
            const float fmp = 0.25f * (bp[0] + bp[1] + bp[WF] + bp[WF + 1]);
            const float fmf = 0.25f * (bf[0] + bf[1] + bf[WF] + bf[WF + 1]);
            dot  += fmp * fmf;
            nsq  += fmp * fmp;
            snsq += fmf * fmf;
        }
    }
    dot  = wave_reduce_sum(dot);
    nsq  = wave_reduce_sum(nsq);
    snsq = wave_reduce_sum(snsq);

    if (lane == 0) {
        float l = 0.f;
        if (active)
            l = 1.0f - dot / (fmaxf(sqrtf(nsq), EPS_F) * fmaxf(sqrtf(snsq), EPS_F));
        ws->loss[p] = l;
    }
}

// Finish: single block reduces the 1536 per-point losses, divides, writes out.
__global__ __launch_bounds__(256) void finish_kernel(
    const WsLayout* __restrict__ ws,
    float*          __restrict__ out)
{
    __shared__ float s_red[4];
    const int tid = threadIdx.x;
    float s = 0.f;
    #pragma unroll
    for (int i = 0; i < P_TOT / 256; ++i) s += ws->loss[tid + 256 * i];
    s = wave_reduce_sum(s);
    const int lane = tid & 63, wave = tid >> 6;
    if (lane == 0) s_red[wave] = s;
    __syncthreads();
    if (tid == 0) {
        const float total = s_red[0] + s_red[1] + s_red[2] + s_red[3];
        const int   cnt   = ws->count;
        out[0] = (cnt > 0) ? total / (float)cnt : 0.0f;
    }
}

extern "C" void kernel_launch(void* const* d_in, const int* in_sizes, int n_in,
                              void* d_out, int out_size, void* d_ws, size_t ws_size,
                              hipStream_t stream) {
    const float* boxes = (const float*)d_in[0];
    const float* feats = (const float*)d_in[1];
    const float* Km    = (const float*)d_in[2];
    const float* Tm    = (const float*)d_in[3];
    const int*   img   = (const int*)d_in[4];
    float* out = (float*)d_out;
    WsLayout* ws = (WsLayout*)d_ws;

    hipLaunchKernelGGL(fused_kernel, dim3(P_TOT / 4), dim3(256), 0, stream,
                       boxes, feats, Km, Tm, img, ws);
    hipLaunchKernelGGL(finish_kernel, dim3(1), dim3(256), 0, stream,
                       ws, out);
}